// Round 1
// baseline (730.144 us; speedup 1.0000x reference)
//
#include <hip/hip_runtime.h>
#include <hip/hip_bf16.h>

constexpr int HID = 256;
constexpr int HEADS = 4;
constexpr int CC = 64;       // channels per head
constexpr float NEG = 0.2f;
constexpr float EPS = 1e-5f;

// ---------------- CSR build ----------------

__global__ void k_init(int* deg, int* cursor, int* cls_lo, int* cls_hi, int n_new, int B) {
    int i = blockIdx.x * blockDim.x + threadIdx.x;
    if (i < n_new) { deg[i] = 0; cursor[i] = 0; }
    if (i < B) { cls_lo[i] = 0; cls_hi[i] = 0; }
}

__global__ void k_count(const int* __restrict__ dst0, int* deg, int E, int B) {
    int e = blockIdx.x * blockDim.x + threadIdx.x;
    if (e < E) atomicAdd(&deg[dst0[e] + B], 1);
}

// exclusive scan of deg -> off[0..n], single block of 256
__global__ void k_scan(const int* __restrict__ deg, int* __restrict__ off, int n) {
    __shared__ int tile[256];
    __shared__ int carry_s;
    int t = threadIdx.x;
    if (t == 0) { carry_s = 0; off[0] = 0; }
    __syncthreads();
    for (int base = 0; base < n; base += 256) {
        int i = base + t;
        int v = (i < n) ? deg[i] : 0;
        tile[t] = v;
        __syncthreads();
        for (int o = 1; o < 256; o <<= 1) {
            int add = (t >= o) ? tile[t - o] : 0;
            __syncthreads();
            tile[t] += add;
            __syncthreads();
        }
        int carry = carry_s;
        int total = tile[255];
        if (i < n) off[i + 1] = carry + tile[t];
        __syncthreads();
        if (t == 0) carry_s = carry + total;
        __syncthreads();
    }
}

__global__ void k_fill(const int* __restrict__ src0, const int* __restrict__ dst0,
                       const int* __restrict__ off, int* cursor, int* __restrict__ csr,
                       int E, int B) {
    int e = blockIdx.x * blockDim.x + threadIdx.x;
    if (e < E) {
        int d = dst0[e] + B;
        int p = atomicAdd(&cursor[d], 1);
        csr[off[d] + p] = src0[e] + B;
    }
}

// batch is sorted non-decreasing: find contiguous node range per graph id
__global__ void k_bounds(const int* __restrict__ batch, int* lo, int* hi, int N) {
    int i = blockIdx.x * blockDim.x + threadIdx.x;
    if (i < N) {
        int b = batch[i];
        if (i == 0 || batch[i - 1] != b) lo[b] = i;
        if (i == N - 1 || batch[i + 1] != b) hi[b] = i + 1;
    }
}

__global__ void k_cls_rows(const float* __restrict__ cls_token, float* __restrict__ h, int B) {
    int i = blockIdx.x * blockDim.x + threadIdx.x;
    if (i < B * HID) h[i] = cls_token[i & (HID - 1)];
}

// ---------------- GEMM: out[row][j] = sum_k A[row][k]*W[k][j] (+bias) ----------------
// block = 256 threads (thread j = output column), 8 rows per block.
// Optionally computes per-head attention logits al_s/al_d (wave w == head w).

template <int K>
__global__ __launch_bounds__(256) void k_gemm(
    const float* __restrict__ A, const float* __restrict__ Wm,
    const float* __restrict__ bias, float* __restrict__ out, int rows,
    const float* __restrict__ att_s, const float* __restrict__ att_d,
    float* __restrict__ al_s, float* __restrict__ al_d)
{
    __shared__ float As[8][K];
    int t = threadIdx.x;
    int base = blockIdx.x * 8;
#pragma unroll
    for (int r = 0; r < 8; ++r) {
        int row = base + r;
        if (K == 256) {
            As[r][t] = (row < rows) ? A[(size_t)row * K + t] : 0.f;
        } else {
            if (t < K) As[r][t] = (row < rows) ? A[(size_t)row * K + t] : 0.f;
        }
    }
    __syncthreads();
    float acc[8] = {0.f, 0.f, 0.f, 0.f, 0.f, 0.f, 0.f, 0.f};
#pragma unroll 8
    for (int k = 0; k < K; ++k) {
        float w = Wm[k * HID + t];
#pragma unroll
        for (int r = 0; r < 8; ++r) acc[r] += As[r][k] * w;
    }
    float b = bias ? bias[t] : 0.f;
#pragma unroll
    for (int r = 0; r < 8; ++r) {
        int row = base + r;
        if (row < rows) out[(size_t)row * HID + t] = acc[r] + b;
    }
    if (att_s) {
        int w = t >> 6, lane = t & 63;
        float as = att_s[t], ad = att_d[t];
#pragma unroll
        for (int r = 0; r < 8; ++r) {
            float ps = acc[r] * as;
            float pd = acc[r] * ad;
#pragma unroll
            for (int o = 32; o > 0; o >>= 1) {
                ps += __shfl_xor(ps, o, 64);
                pd += __shfl_xor(pd, o, 64);
            }
            int row = base + r;
            if (lane == 0 && row < rows) {
                al_s[row * HEADS + w] = ps;
                al_d[row * HEADS + w] = pd;
            }
        }
    }
}

// ---------------- GAT aggregation + bias + residual + LayerNorm ----------------
// One block per destination node. 4 waves = 4 heads, lane = channel.

__global__ __launch_bounds__(256) void k_agg(
    const float* __restrict__ h, const float* __restrict__ xs,
    const float* __restrict__ al_s, const float* __restrict__ al_d,
    const int* __restrict__ off, const int* __restrict__ csr,
    const int* __restrict__ batch, const int* __restrict__ cls_lo,
    const int* __restrict__ cls_hi,
    const float* __restrict__ b_gat, const float* __restrict__ ln_g,
    const float* __restrict__ ln_b,
    float* __restrict__ h_out, int n_new, int B)
{
    int n = blockIdx.x;
    int t = threadIdx.x, w = t >> 6, lane = t & 63;

    int gbeg = 0, gdeg = 0, cbeg = 0, cdeg = 0;
    if (n >= B) {
        gbeg = off[n];
        gdeg = off[n + 1] - gbeg;
        cdeg = 1;                    // one CLS->node edge
    } else {
        cbeg = cls_lo[n];
        cdeg = cls_hi[n] - cbeg;     // node->CLS edges, contiguous node range
    }
    int cnt = gdeg + cdeg + 1;       // + self loop
    float ald = al_d[n * HEADS + w];

    // phase 1: online softmax (max + denom) per head
    float m = -1e30f, s = 0.f;
    for (int e = lane; e < cnt; e += 64) {
        int src;
        if (e < gdeg) src = csr[gbeg + e];
        else if (e < gdeg + cdeg) src = (n >= B) ? batch[n - B] : (B + cbeg + (e - gdeg));
        else src = n;
        float v = al_s[src * HEADS + w] + ald;
        v = v > 0.f ? v : NEG * v;
        float mn = fmaxf(m, v);
        s = s * __expf(m - mn) + __expf(v - mn);
        m = mn;
    }
#pragma unroll
    for (int o = 32; o > 0; o >>= 1) {
        float m2 = __shfl_xor(m, o, 64);
        float s2 = __shfl_xor(s, o, 64);
        float mn = fmaxf(m, m2);
        s = s * __expf(m - mn) + s2 * __expf(m2 - mn);
        m = mn;
    }
    float inv_den = 1.f / (s + 1e-16f);

    // phase 2: weighted accumulation of xs[src]
    float acc = 0.f;
    const float* xcol = xs + (w * CC + lane);
    for (int e = 0; e < cnt; ++e) {
        int src;
        if (e < gdeg) src = csr[gbeg + e];
        else if (e < gdeg + cdeg) src = (n >= B) ? batch[n - B] : (B + cbeg + (e - gdeg));
        else src = n;
        float v = al_s[src * HEADS + w] + ald;
        v = v > 0.f ? v : NEG * v;
        float a = __expf(v - m);
        acc += a * xcol[(size_t)src * HID];
    }
    acc = acc * inv_den + b_gat[t];
    float resid = h[(size_t)n * HID + t] + acc;

    // LayerNorm over 256 channels
    __shared__ float red[8];
    float v1 = resid;
#pragma unroll
    for (int o = 32; o > 0; o >>= 1) v1 += __shfl_xor(v1, o, 64);
    if (lane == 0) red[w] = v1;
    __syncthreads();
    float mu = (red[0] + red[1] + red[2] + red[3]) * (1.f / HID);
    float d = resid - mu;
    float v2 = d * d;
#pragma unroll
    for (int o = 32; o > 0; o >>= 1) v2 += __shfl_xor(v2, o, 64);
    if (lane == 0) red[4 + w] = v2;
    __syncthreads();
    float var = (red[4] + red[5] + red[6] + red[7]) * (1.f / HID);
    float rs = rsqrtf(var + EPS);
    h_out[(size_t)n * HID + t] = d * rs * ln_g[t] + ln_b[t];
}

// ---------------- output projection (B x 256 @ 256 x 256) ----------------

__global__ __launch_bounds__(256) void k_out(
    const float* __restrict__ h, const float* __restrict__ Wm,
    const float* __restrict__ bias, float* __restrict__ z)
{
    __shared__ float hs[HID];
    int b = blockIdx.x, t = threadIdx.x;
    hs[t] = h[(size_t)b * HID + t];
    __syncthreads();
    float acc = bias[t];
#pragma unroll 8
    for (int k = 0; k < HID; ++k) acc += hs[k] * Wm[k * HID + t];
    z[(size_t)b * HID + t] = acc;
}

// ---------------- launch ----------------

extern "C" void kernel_launch(void* const* d_in, const int* in_sizes, int n_in,
                              void* d_out, int out_size, void* d_ws, size_t ws_size,
                              hipStream_t stream) {
    const float* x      = (const float*)d_in[0];
    const int*   ei     = (const int*)d_in[1];
    const int*   batch  = (const int*)d_in[2];
    const float* W_in   = (const float*)d_in[3];
    const float* b_in   = (const float*)d_in[4];
    const float* cls    = (const float*)d_in[5];
    const float* W_gat  = (const float*)d_in[6];
    const float* att_s  = (const float*)d_in[7];
    const float* att_d  = (const float*)d_in[8];
    const float* b_gat  = (const float*)d_in[9];
    const float* ln_g   = (const float*)d_in[10];
    const float* ln_b   = (const float*)d_in[11];
    const float* W_out  = (const float*)d_in[12];
    const float* b_out  = (const float*)d_in[13];

    const int N = in_sizes[0] / 128;
    const int E = in_sizes[1] / 2;
    const int B = 64;
    const int n_new = N + B;
    const int* src0 = ei;
    const int* dst0 = ei + E;

    char* p = (char*)d_ws;
    auto alloc = [&](size_t bytes) -> void* {
        void* r = (void*)p;
        p += (bytes + 255) & ~(size_t)255;
        return r;
    };
    int*   off    = (int*)alloc((size_t)(n_new + 1) * 4);
    int*   deg    = (int*)alloc((size_t)n_new * 4);
    int*   cursor = (int*)alloc((size_t)n_new * 4);
    int*   csr    = (int*)alloc((size_t)E * 4);
    int*   lo     = (int*)alloc((size_t)B * 4);
    int*   hi     = (int*)alloc((size_t)B * 4);
    float* h0     = (float*)alloc((size_t)n_new * HID * 4);
    float* h1     = (float*)alloc((size_t)n_new * HID * 4);
    float* xs     = (float*)alloc((size_t)n_new * HID * 4);
    float* als    = (float*)alloc((size_t)n_new * HEADS * 4);
    float* aldv   = (float*)alloc((size_t)n_new * HEADS * 4);

    k_init<<<(n_new + 255) / 256, 256, 0, stream>>>(deg, cursor, lo, hi, n_new, B);
    k_count<<<(E + 255) / 256, 256, 0, stream>>>(dst0, deg, E, B);
    k_scan<<<1, 256, 0, stream>>>(deg, off, n_new);
    k_fill<<<(E + 255) / 256, 256, 0, stream>>>(src0, dst0, off, cursor, csr, E, B);
    k_bounds<<<(N + 255) / 256, 256, 0, stream>>>(batch, lo, hi, N);

    k_cls_rows<<<(B * HID + 255) / 256, 256, 0, stream>>>(cls, h0, B);
    k_gemm<128><<<(N + 7) / 8, 256, 0, stream>>>(
        x, W_in, b_in, h0 + (size_t)B * HID, N, nullptr, nullptr, nullptr, nullptr);

    float* cur = h0;
    float* nxt = h1;
    for (int l = 0; l < 3; ++l) {
        k_gemm<256><<<(n_new + 7) / 8, 256, 0, stream>>>(
            cur, W_gat + (size_t)l * HID * HID, nullptr, xs, n_new,
            att_s + l * HID, att_d + l * HID, als, aldv);
        k_agg<<<n_new, 256, 0, stream>>>(
            cur, xs, als, aldv, off, csr, batch, lo, hi,
            b_gat + l * HID, ln_g + l * HID, ln_b + l * HID, nxt, n_new, B);
        float* tmp = cur; cur = nxt; nxt = tmp;
    }
    k_out<<<B, 256, 0, stream>>>(cur, W_out, b_out, (float*)d_out);
}

// Round 2
// 648.041 us; speedup vs baseline: 1.1267x; 1.1267x over previous
//
#include <hip/hip_runtime.h>
#include <hip/hip_bf16.h>

constexpr int HID = 256;
constexpr float NEG = 0.2f;
constexpr float EPS = 1e-5f;
constexpr int MAXE = 128;

typedef __attribute__((ext_vector_type(8))) short bf16x8;
typedef __attribute__((ext_vector_type(4))) float f32x4;

static __device__ __forceinline__ unsigned short f2bf(float f) {
    unsigned u = __builtin_bit_cast(unsigned, f);
    u += 0x7fffu + ((u >> 16) & 1u);
    return (unsigned short)(u >> 16);
}
static __device__ __forceinline__ float bf2f(unsigned short h) {
    return __builtin_bit_cast(float, ((unsigned)h) << 16);
}

// ---------------- CSR build ----------------

__global__ void k_init(int* deg, int* cursor, int* cls_lo, int* cls_hi, int n_new, int B) {
    int i = blockIdx.x * blockDim.x + threadIdx.x;
    if (i < n_new) { deg[i] = 0; cursor[i] = 0; }
    if (i < B) { cls_lo[i] = 0; cls_hi[i] = 0; }
}

__global__ void k_count(const int* __restrict__ dst0, int* deg, int E, int B) {
    int e = blockIdx.x * blockDim.x + threadIdx.x;
    if (e < E) atomicAdd(&deg[dst0[e] + B], 1);
}

// exclusive scan, single block of 1024, shfl-based
__global__ void k_scan(const int* __restrict__ deg, int* __restrict__ off, int n) {
    __shared__ int wsum[16];
    __shared__ int carry_s;
    int t = threadIdx.x, w = t >> 6, lane = t & 63;
    if (t == 0) { carry_s = 0; off[0] = 0; }
    __syncthreads();
    for (int base = 0; base < n; base += 1024) {
        int i = base + t;
        int v = (i < n) ? deg[i] : 0;
        int x = v;
#pragma unroll
        for (int o = 1; o < 64; o <<= 1) {
            int u = __shfl_up(x, o, 64);
            if (lane >= o) x += u;
        }
        if (lane == 63) wsum[w] = x;
        __syncthreads();
        int wpre = 0, total = 0;
#pragma unroll
        for (int k = 0; k < 16; ++k) {
            int s = wsum[k];
            wpre += (k < w) ? s : 0;
            total += s;
        }
        int c = carry_s;
        if (i < n) off[i + 1] = c + wpre + x;
        __syncthreads();
        if (t == 0) carry_s = c + total;
        __syncthreads();
    }
}

__global__ void k_fill(const int* __restrict__ src0, const int* __restrict__ dst0,
                       const int* __restrict__ off, int* cursor, int* __restrict__ csr,
                       int E, int B) {
    int e = blockIdx.x * blockDim.x + threadIdx.x;
    if (e < E) {
        int d = dst0[e] + B;
        int p = atomicAdd(&cursor[d], 1);
        csr[off[d] + p] = src0[e] + B;
    }
}

__global__ void k_bounds(const int* __restrict__ batch, int* lo, int* hi, int N) {
    int i = blockIdx.x * blockDim.x + threadIdx.x;
    if (i < N) {
        int b = batch[i];
        if (i == 0 || batch[i - 1] != b) lo[b] = i;
        if (i == N - 1 || batch[i + 1] != b) hi[b] = i + 1;
    }
}

__global__ void k_cls(const float* __restrict__ cls_token, ushort* __restrict__ h, int B) {
    int i = blockIdx.x * blockDim.x + threadIdx.x;
    if (i < B * HID) h[i] = f2bf(cls_token[i & (HID - 1)]);
}

__global__ void k_cvt(const float* __restrict__ in, ushort* __restrict__ out, int n4) {
    int i = blockIdx.x * blockDim.x + threadIdx.x;
    if (i < n4) {
        float4 v = ((const float4*)in)[i];
        ushort4 o;
        o.x = f2bf(v.x); o.y = f2bf(v.y); o.z = f2bf(v.z); o.w = f2bf(v.w);
        ((ushort4*)out)[i] = o;
    }
}

// Pre-fragment W (K x 256 fp32, row-major) into MFMA B-fragment-major bf16:
// entry q = (kk*16 + nf)*64 + lane holds 8 contiguous-k values
// B[kk*32 + (lane>>4)*8 + j][nf*16 + (lane&15)]
__global__ void k_frag(const float* __restrict__ W, ushort* __restrict__ out,
                       int KS, int nmat) {
    int q = blockIdx.x * blockDim.x + threadIdx.x;
    int per = KS * 1024;
    if (q >= per * nmat) return;
    int mat = q / per, r = q - mat * per;
    int l = r & 63, nf = (r >> 6) & 15, kk = r >> 10;
    const float* Wm = W + (size_t)mat * KS * 32 * 256;
    int kb = kk * 32 + ((l >> 4) << 3);
    int col = nf * 16 + (l & 15);
    bf16x8 v;
#pragma unroll
    for (int j = 0; j < 8; ++j) v[j] = (short)f2bf(Wm[(size_t)(kb + j) * 256 + col]);
    *(bf16x8*)(out + (size_t)q * 8) = v;
}

// ---------------- MFMA GEMM: out[row][0:256] = A[row][0:K] @ W ----------------
// block = 256 (4 waves), 32 rows/wave (2 M-frags), 128 rows/block, no LDS.

template <int KS, bool ATT, bool BIAS>
__global__ __launch_bounds__(256, 1) void k_mgemm(
    const ushort* __restrict__ A, const ushort* __restrict__ Wf,
    const float* __restrict__ bias, ushort* __restrict__ outb,
    const float* __restrict__ att_s, const float* __restrict__ att_d,
    float* __restrict__ al_s, float* __restrict__ al_d, int rows)
{
    constexpr int K = KS * 32;
    int lane = threadIdx.x & 63, w = threadIdx.x >> 6;
    int rbase = blockIdx.x * 128 + w * 32;
    int arow0 = rbase + (lane & 15);
    int kofs = (lane >> 4) << 3;

    f32x4 acc[2][16];
#pragma unroll
    for (int mf = 0; mf < 2; ++mf)
#pragma unroll
        for (int nf = 0; nf < 16; ++nf) acc[mf][nf] = (f32x4){0.f, 0.f, 0.f, 0.f};

    const ushort* a0p = A + (size_t)arow0 * K + kofs;
    const ushort* a1p = a0p + (size_t)16 * K;
    bool g0 = arow0 < rows, g1 = (arow0 + 16) < rows;

#pragma unroll
    for (int kk = 0; kk < KS; ++kk) {
        bf16x8 af0 = {0, 0, 0, 0, 0, 0, 0, 0}, af1 = {0, 0, 0, 0, 0, 0, 0, 0};
        if (g0) af0 = *(const bf16x8*)(a0p + kk * 32);
        if (g1) af1 = *(const bf16x8*)(a1p + kk * 32);
        const bf16x8* wp = ((const bf16x8*)Wf) + (size_t)(kk * 16) * 64 + lane;
#pragma unroll
        for (int nf = 0; nf < 16; ++nf) {
            bf16x8 bv = wp[nf * 64];
            acc[0][nf] = __builtin_amdgcn_mfma_f32_16x16x32_bf16(af0, bv, acc[0][nf], 0, 0, 0);
            acc[1][nf] = __builtin_amdgcn_mfma_f32_16x16x32_bf16(af1, bv, acc[1][nf], 0, 0, 0);
        }
    }

    int rg = (lane >> 4) * 4;
    int c0 = lane & 15;
    float bv[16];
    if (BIAS) {
#pragma unroll
        for (int nf = 0; nf < 16; ++nf) bv[nf] = bias[nf * 16 + c0];
    }
#pragma unroll
    for (int mf = 0; mf < 2; ++mf)
#pragma unroll
        for (int r = 0; r < 4; ++r) {
            int row = rbase + mf * 16 + rg + r;
            if (row < rows) {
#pragma unroll
                for (int nf = 0; nf < 16; ++nf) {
                    float v = acc[mf][nf][r];
                    if (BIAS) v += bv[nf];
                    outb[(size_t)row * HID + nf * 16 + c0] = f2bf(v);
                }
            }
        }

    if (ATT) {
        float as[16], ad[16];
#pragma unroll
        for (int nf = 0; nf < 16; ++nf) {
            as[nf] = att_s[nf * 16 + c0];
            ad[nf] = att_d[nf * 16 + c0];
        }
#pragma unroll
        for (int mf = 0; mf < 2; ++mf)
#pragma unroll
            for (int r = 0; r < 4; ++r) {
                float ps[4] = {0.f, 0.f, 0.f, 0.f}, pd[4] = {0.f, 0.f, 0.f, 0.f};
#pragma unroll
                for (int nf = 0; nf < 16; ++nf) {
                    float v = acc[mf][nf][r];
                    ps[nf >> 2] += v * as[nf];
                    pd[nf >> 2] += v * ad[nf];
                }
#pragma unroll
                for (int o = 1; o < 16; o <<= 1) {
#pragma unroll
                    for (int h = 0; h < 4; ++h) {
                        ps[h] += __shfl_xor(ps[h], o, 64);
                        pd[h] += __shfl_xor(pd[h], o, 64);
                    }
                }
                int row = rbase + mf * 16 + rg + r;
                if (c0 == 0 && row < rows) {
                    float4 vs, vd;
                    vs.x = ps[0]; vs.y = ps[1]; vs.z = ps[2]; vs.w = ps[3];
                    vd.x = pd[0]; vd.y = pd[1]; vd.z = pd[2]; vd.w = pd[3];
                    *(float4*)(al_s + row * 4) = vs;
                    *(float4*)(al_d + row * 4) = vd;
                }
            }
    }
}

// ---------------- GAT aggregation + bias + residual + LayerNorm ----------------
// One WAVE per destination node (4 nodes/block). lane covers channels lane*4..+3,
// head = lane>>4. Per-edge logits cached in LDS.

__global__ __launch_bounds__(256) void k_agg(
    const ushort* __restrict__ hb, const ushort* __restrict__ xs,
    const float* __restrict__ al_s, const float* __restrict__ al_d,
    const int* __restrict__ off, const int* __restrict__ csr,
    const int* __restrict__ batch, const int* __restrict__ lo,
    const int* __restrict__ hi,
    const float* __restrict__ b_gat, const float* __restrict__ ln_g,
    const float* __restrict__ ln_b,
    ushort* __restrict__ h_out, int n_new, int B)
{
    __shared__ int s_src[4][MAXE];
    __shared__ float s_v[4][4][132];
    int t = threadIdx.x, w = t >> 6, lane = t & 63;
    int n = blockIdx.x * 4 + w;
    if (n >= n_new) return;

    int gbeg = 0, gdeg = 0, cbeg = 0, cdeg = 0;
    if (n >= B) { gbeg = off[n]; gdeg = off[n + 1] - gbeg; cdeg = 1; }
    else { cbeg = lo[n]; cdeg = hi[n] - cbeg; }
    int cnt = gdeg + cdeg + 1;

    float4 ald = *(const float4*)(al_d + n * 4);

    // fill LDS with per-edge logits, track per-head max
    float mx0 = -1e30f, mx1 = -1e30f, mx2 = -1e30f, mx3 = -1e30f;
    for (int e = lane; e < cnt; e += 64) {
        int src;
        if (e < gdeg) src = csr[gbeg + e];
        else if (e < gdeg + cdeg) src = (n >= B) ? batch[n - B] : (B + cbeg + (e - gdeg));
        else src = n;
        float4 a4 = *(const float4*)(al_s + src * 4);
        float v0 = a4.x + ald.x; v0 = v0 > 0.f ? v0 : NEG * v0;
        float v1 = a4.y + ald.y; v1 = v1 > 0.f ? v1 : NEG * v1;
        float v2 = a4.z + ald.z; v2 = v2 > 0.f ? v2 : NEG * v2;
        float v3 = a4.w + ald.w; v3 = v3 > 0.f ? v3 : NEG * v3;
        if (e < MAXE) {
            s_src[w][e] = src;
            s_v[w][0][e] = v0; s_v[w][1][e] = v1; s_v[w][2][e] = v2; s_v[w][3][e] = v3;
        }
        mx0 = fmaxf(mx0, v0); mx1 = fmaxf(mx1, v1);
        mx2 = fmaxf(mx2, v2); mx3 = fmaxf(mx3, v3);
    }
    __builtin_amdgcn_wave_barrier();
#pragma unroll
    for (int o = 32; o > 0; o >>= 1) {
        mx0 = fmaxf(mx0, __shfl_xor(mx0, o, 64));
        mx1 = fmaxf(mx1, __shfl_xor(mx1, o, 64));
        mx2 = fmaxf(mx2, __shfl_xor(mx2, o, 64));
        mx3 = fmaxf(mx3, __shfl_xor(mx3, o, 64));
    }
    // per-head denominators
    float s0 = 0.f, s1 = 0.f, s2 = 0.f, s3 = 0.f;
    for (int e = lane; e < cnt; e += 64) {
        float v0, v1, v2, v3;
        if (e < MAXE) {
            v0 = s_v[w][0][e]; v1 = s_v[w][1][e]; v2 = s_v[w][2][e]; v3 = s_v[w][3][e];
        } else {
            int src;
            if (e < gdeg) src = csr[gbeg + e];
            else if (e < gdeg + cdeg) src = (n >= B) ? batch[n - B] : (B + cbeg + (e - gdeg));
            else src = n;
            float4 a4 = *(const float4*)(al_s + src * 4);
            v0 = a4.x + ald.x; v0 = v0 > 0.f ? v0 : NEG * v0;
            v1 = a4.y + ald.y; v1 = v1 > 0.f ? v1 : NEG * v1;
            v2 = a4.z + ald.z; v2 = v2 > 0.f ? v2 : NEG * v2;
            v3 = a4.w + ald.w; v3 = v3 > 0.f ? v3 : NEG * v3;
        }
        s0 += __expf(v0 - mx0); s1 += __expf(v1 - mx1);
        s2 += __expf(v2 - mx2); s3 += __expf(v3 - mx3);
    }
#pragma unroll
    for (int o = 32; o > 0; o >>= 1) {
        s0 += __shfl_xor(s0, o, 64); s1 += __shfl_xor(s1, o, 64);
        s2 += __shfl_xor(s2, o, 64); s3 += __shfl_xor(s3, o, 64);
    }
    int hsel = lane >> 4;
    float m_h = hsel == 0 ? mx0 : hsel == 1 ? mx1 : hsel == 2 ? mx2 : mx3;
    float s_h = hsel == 0 ? s0 : hsel == 1 ? s1 : hsel == 2 ? s2 : s3;
    float inv_h = 1.f / (s_h + 1e-16f);

    // weighted accumulation, 4 channels per lane
    float acc0 = 0.f, acc1 = 0.f, acc2 = 0.f, acc3 = 0.f;
    const float* vrow = &s_v[w][0][0] + hsel * 132;
#pragma unroll 2
    for (int e = 0; e < cnt; ++e) {
        int src; float vh;
        if (e < MAXE) {
            src = s_src[w][e];
            vh = vrow[e];
        } else {
            if (e < gdeg) src = csr[gbeg + e];
            else if (e < gdeg + cdeg) src = (n >= B) ? batch[n - B] : (B + cbeg + (e - gdeg));
            else src = n;
            float4 a4 = *(const float4*)(al_s + src * 4);
            float v0 = a4.x + ald.x; v0 = v0 > 0.f ? v0 : NEG * v0;
            float v1 = a4.y + ald.y; v1 = v1 > 0.f ? v1 : NEG * v1;
            float v2 = a4.z + ald.z; v2 = v2 > 0.f ? v2 : NEG * v2;
            float v3 = a4.w + ald.w; v3 = v3 > 0.f ? v3 : NEG * v3;
            vh = hsel == 0 ? v0 : hsel == 1 ? v1 : hsel == 2 ? v2 : v3;
        }
        float a = __expf(vh - m_h);
        ushort4 xv = *((const ushort4*)(xs + (size_t)src * HID) + lane);
        acc0 += a * bf2f(xv.x); acc1 += a * bf2f(xv.y);
        acc2 += a * bf2f(xv.z); acc3 += a * bf2f(xv.w);
    }

    float4 bg = *(const float4*)(b_gat + lane * 4);
    ushort4 hv = *((const ushort4*)(hb + (size_t)n * HID) + lane);
    float r0 = bf2f(hv.x) + acc0 * inv_h + bg.x;
    float r1 = bf2f(hv.y) + acc1 * inv_h + bg.y;
    float r2 = bf2f(hv.z) + acc2 * inv_h + bg.z;
    float r3 = bf2f(hv.w) + acc3 * inv_h + bg.w;

    float ssum = r0 + r1 + r2 + r3;
#pragma unroll
    for (int o = 32; o > 0; o >>= 1) ssum += __shfl_xor(ssum, o, 64);
    float mu = ssum * (1.f / HID);
    float d0 = r0 - mu, d1 = r1 - mu, d2 = r2 - mu, d3 = r3 - mu;
    float vsum = d0 * d0 + d1 * d1 + d2 * d2 + d3 * d3;
#pragma unroll
    for (int o = 32; o > 0; o >>= 1) vsum += __shfl_xor(vsum, o, 64);
    float rs = rsqrtf(vsum * (1.f / HID) + EPS);
    float4 g = *(const float4*)(ln_g + lane * 4);
    float4 bb = *(const float4*)(ln_b + lane * 4);
    ushort4 o4;
    o4.x = f2bf(d0 * rs * g.x + bb.x);
    o4.y = f2bf(d1 * rs * g.y + bb.y);
    o4.z = f2bf(d2 * rs * g.z + bb.z);
    o4.w = f2bf(d3 * rs * g.w + bb.w);
    *((ushort4*)(h_out + (size_t)n * HID) + lane) = o4;
}

// ---------------- output projection (B x 256 @ 256 x 256) ----------------

__global__ __launch_bounds__(256) void k_out(
    const ushort* __restrict__ h, const float* __restrict__ Wm,
    const float* __restrict__ bias, float* __restrict__ z)
{
    __shared__ float hs[HID];
    int b = blockIdx.x, t = threadIdx.x;
    hs[t] = bf2f(h[(size_t)b * HID + t]);
    __syncthreads();
    float acc = bias[t];
#pragma unroll 8
    for (int k = 0; k < HID; ++k) acc += hs[k] * Wm[k * HID + t];
    z[(size_t)b * HID + t] = acc;
}

// ---------------- launch ----------------

extern "C" void kernel_launch(void* const* d_in, const int* in_sizes, int n_in,
                              void* d_out, int out_size, void* d_ws, size_t ws_size,
                              hipStream_t stream) {
    const float* x      = (const float*)d_in[0];
    const int*   ei     = (const int*)d_in[1];
    const int*   batch  = (const int*)d_in[2];
    const float* W_in   = (const float*)d_in[3];
    const float* b_in   = (const float*)d_in[4];
    const float* cls    = (const float*)d_in[5];
    const float* W_gat  = (const float*)d_in[6];
    const float* att_s  = (const float*)d_in[7];
    const float* att_d  = (const float*)d_in[8];
    const float* b_gat  = (const float*)d_in[9];
    const float* ln_g   = (const float*)d_in[10];
    const float* ln_b   = (const float*)d_in[11];
    const float* W_out  = (const float*)d_in[12];
    const float* b_out  = (const float*)d_in[13];

    const int N = in_sizes[0] / 128;
    const int E = in_sizes[1] / 2;
    const int B = 64;
    const int n_new = N + B;
    const int* src0 = ei;
    const int* dst0 = ei + E;

    char* p = (char*)d_ws;
    auto alloc = [&](size_t bytes) -> void* {
        void* r = (void*)p;
        p += (bytes + 255) & ~(size_t)255;
        return r;
    };
    int*    off    = (int*)alloc((size_t)(n_new + 1) * 4);
    int*    deg    = (int*)alloc((size_t)n_new * 4);
    int*    cursor = (int*)alloc((size_t)n_new * 4);
    int*    csr    = (int*)alloc((size_t)E * 4);
    int*    lo     = (int*)alloc((size_t)B * 4);
    int*    hi     = (int*)alloc((size_t)B * 4);
    ushort* xb     = (ushort*)alloc((size_t)N * 128 * 2);
    ushort* h0b    = (ushort*)alloc((size_t)n_new * HID * 2);
    ushort* h1b    = (ushort*)alloc((size_t)n_new * HID * 2);
    ushort* xsb    = (ushort*)alloc((size_t)n_new * HID * 2);
    float*  als    = (float*)alloc((size_t)n_new * 4 * 4);
    float*  aldv   = (float*)alloc((size_t)n_new * 4 * 4);
    ushort* wf_in  = (ushort*)alloc((size_t)4 * 1024 * 8 * 2);
    ushort* wf_gat = (ushort*)alloc((size_t)3 * 8 * 1024 * 8 * 2);

    k_init<<<(n_new + 255) / 256, 256, 0, stream>>>(deg, cursor, lo, hi, n_new, B);
    k_count<<<(E + 255) / 256, 256, 0, stream>>>(dst0, deg, E, B);
    k_scan<<<1, 1024, 0, stream>>>(deg, off, n_new);
    k_fill<<<(E + 255) / 256, 256, 0, stream>>>(src0, dst0, off, cursor, csr, E, B);
    k_bounds<<<(N + 255) / 256, 256, 0, stream>>>(batch, lo, hi, N);

    k_cvt<<<(N * 128 / 4 + 255) / 256, 256, 0, stream>>>(x, xb, N * 128 / 4);
    k_cls<<<(B * HID + 255) / 256, 256, 0, stream>>>(cls, h0b, B);
    k_frag<<<(4 * 1024 + 255) / 256, 256, 0, stream>>>(W_in, wf_in, 4, 1);
    k_frag<<<(3 * 8 * 1024 + 255) / 256, 256, 0, stream>>>(W_gat, wf_gat, 8, 3);

    k_mgemm<4, false, true><<<(N + 127) / 128, 256, 0, stream>>>(
        xb, wf_in, b_in, h0b + (size_t)B * HID, nullptr, nullptr, nullptr, nullptr, N);

    ushort* cur = h0b;
    ushort* nxt = h1b;
    for (int l = 0; l < 3; ++l) {
        k_mgemm<8, true, false><<<(n_new + 127) / 128, 256, 0, stream>>>(
            cur, wf_gat + (size_t)l * 65536, nullptr, xsb,
            att_s + l * HID, att_d + l * HID, als, aldv, n_new);
        k_agg<<<(n_new + 3) / 4, 256, 0, stream>>>(
            cur, xsb, als, aldv, off, csr, batch, lo, hi,
            b_gat + l * HID, ln_g + l * HID, ln_b + l * HID, nxt, n_new, B);
        ushort* tmp = cur; cur = nxt; nxt = tmp;
    }
    k_out<<<B, 256, 0, stream>>>(cur, W_out, b_out, (float*)d_out);
}

// Round 3
// 367.949 us; speedup vs baseline: 1.9844x; 1.7612x over previous
//
#include <hip/hip_runtime.h>
#include <hip/hip_bf16.h>

constexpr int HID = 256;
constexpr float NEG = 0.2f;
constexpr float EPS = 1e-5f;

typedef __attribute__((ext_vector_type(8))) short bf16x8;
typedef __attribute__((ext_vector_type(4))) float f32x4;

static __device__ __forceinline__ unsigned short f2bf(float f) {
    unsigned u = __builtin_bit_cast(unsigned, f);
    u += 0x7fffu + ((u >> 16) & 1u);
    return (unsigned short)(u >> 16);
}
static __device__ __forceinline__ float bf2f(unsigned short h) {
    return __builtin_bit_cast(float, ((unsigned)h) << 16);
}

// ---------------- CSR build ----------------

__global__ void k_init(int* deg, int* cursor, int* cls_lo, int* cls_hi, int n_new, int B) {
    int i = blockIdx.x * blockDim.x + threadIdx.x;
    if (i < n_new) { deg[i] = 0; cursor[i] = 0; }
    if (i < B) { cls_lo[i] = 0; cls_hi[i] = 0; }
}

__global__ void k_count(const int* __restrict__ dst0, int* deg, int E, int B) {
    int e = blockIdx.x * blockDim.x + threadIdx.x;
    if (e < E) atomicAdd(&deg[dst0[e] + B], 1);
}

// exclusive scan, single block of 1024, shfl-based
__global__ void k_scan(const int* __restrict__ deg, int* __restrict__ off, int n) {
    __shared__ int wsum[16];
    __shared__ int carry_s;
    int t = threadIdx.x, w = t >> 6, lane = t & 63;
    if (t == 0) { carry_s = 0; off[0] = 0; }
    __syncthreads();
    for (int base = 0; base < n; base += 1024) {
        int i = base + t;
        int v = (i < n) ? deg[i] : 0;
        int x = v;
#pragma unroll
        for (int o = 1; o < 64; o <<= 1) {
            int u = __shfl_up(x, o, 64);
            if (lane >= o) x += u;
        }
        if (lane == 63) wsum[w] = x;
        __syncthreads();
        int wpre = 0, total = 0;
#pragma unroll
        for (int k = 0; k < 16; ++k) {
            int s = wsum[k];
            wpre += (k < w) ? s : 0;
            total += s;
        }
        int c = carry_s;
        if (i < n) off[i + 1] = c + wpre + x;
        __syncthreads();
        if (t == 0) carry_s = c + total;
        __syncthreads();
    }
}

__global__ void k_fill(const int* __restrict__ src0, const int* __restrict__ dst0,
                       const int* __restrict__ off, int* cursor, int* __restrict__ csr,
                       int E, int B) {
    int e = blockIdx.x * blockDim.x + threadIdx.x;
    if (e < E) {
        int d = dst0[e] + B;
        int p = atomicAdd(&cursor[d], 1);
        csr[off[d] + p] = src0[e] + B;
    }
}

__global__ void k_bounds(const int* __restrict__ batch, int* lo, int* hi, int N) {
    int i = blockIdx.x * blockDim.x + threadIdx.x;
    if (i < N) {
        int b = batch[i];
        if (i == 0 || batch[i - 1] != b) lo[b] = i;
        if (i == N - 1 || batch[i + 1] != b) hi[b] = i + 1;
    }
}

__global__ void k_cls(const float* __restrict__ cls_token, ushort* __restrict__ h, int B) {
    int i = blockIdx.x * blockDim.x + threadIdx.x;
    if (i < B * HID) h[i] = f2bf(cls_token[i & (HID - 1)]);
}

__global__ void k_cvt(const float* __restrict__ in, ushort* __restrict__ out, int n4) {
    int i = blockIdx.x * blockDim.x + threadIdx.x;
    if (i < n4) {
        float4 v = ((const float4*)in)[i];
        ushort4 o;
        o.x = f2bf(v.x); o.y = f2bf(v.y); o.z = f2bf(v.z); o.w = f2bf(v.w);
        ((ushort4*)out)[i] = o;
    }
}

// Pre-fragment W (K x 256 fp32, row-major) into MFMA B-fragment-major bf16:
// entry q = (kk*16 + nf)*64 + lane holds 8 contiguous-k values
// B[kk*32 + (lane>>4)*8 + j][nf*16 + (lane&15)]
__global__ void k_frag(const float* __restrict__ W, ushort* __restrict__ out,
                       int KS, int nmat) {
    int q = blockIdx.x * blockDim.x + threadIdx.x;
    int per = KS * 1024;
    if (q >= per * nmat) return;
    int mat = q / per, r = q - mat * per;
    int l = r & 63, nf = (r >> 6) & 15, kk = r >> 10;
    const float* Wm = W + (size_t)mat * KS * 32 * 256;
    int kb = kk * 32 + ((l >> 4) << 3);
    int col = nf * 16 + (l & 15);
    bf16x8 v;
#pragma unroll
    for (int j = 0; j < 8; ++j) v[j] = (short)f2bf(Wm[(size_t)(kb + j) * 256 + col]);
    *(bf16x8*)(out + (size_t)q * 8) = v;
}

// ---------------- MFMA GEMM: out[row][0:256] = A[row][0:K] @ W ----------------
// block = 128 (2 waves), 32 rows/wave, 64 rows/block, no LDS.

template <int KS, bool ATT, bool BIAS>
__global__ __launch_bounds__(128, 1) void k_mgemm(
    const ushort* __restrict__ A, const ushort* __restrict__ Wf,
    const float* __restrict__ bias, ushort* __restrict__ outb,
    const float* __restrict__ att_s, const float* __restrict__ att_d,
    float* __restrict__ al_s, float* __restrict__ al_d, int rows)
{
    constexpr int K = KS * 32;
    int lane = threadIdx.x & 63, w = threadIdx.x >> 6;
    int rbase = blockIdx.x * 64 + w * 32;
    int arow0 = rbase + (lane & 15);
    int kofs = (lane >> 4) << 3;

    f32x4 acc[2][16];
#pragma unroll
    for (int mf = 0; mf < 2; ++mf)
#pragma unroll
        for (int nf = 0; nf < 16; ++nf) acc[mf][nf] = (f32x4){0.f, 0.f, 0.f, 0.f};

    const ushort* a0p = A + (size_t)arow0 * K + kofs;
    const ushort* a1p = a0p + (size_t)16 * K;
    bool g0 = arow0 < rows, g1 = (arow0 + 16) < rows;

#pragma unroll
    for (int kk = 0; kk < KS; ++kk) {
        bf16x8 af0 = {0, 0, 0, 0, 0, 0, 0, 0}, af1 = {0, 0, 0, 0, 0, 0, 0, 0};
        if (g0) af0 = *(const bf16x8*)(a0p + kk * 32);
        if (g1) af1 = *(const bf16x8*)(a1p + kk * 32);
        const bf16x8* wp = ((const bf16x8*)Wf) + (size_t)(kk * 16) * 64 + lane;
#pragma unroll
        for (int nf = 0; nf < 16; ++nf) {
            bf16x8 bv = wp[nf * 64];
            acc[0][nf] = __builtin_amdgcn_mfma_f32_16x16x32_bf16(af0, bv, acc[0][nf], 0, 0, 0);
            acc[1][nf] = __builtin_amdgcn_mfma_f32_16x16x32_bf16(af1, bv, acc[1][nf], 0, 0, 0);
        }
    }

    int rg = (lane >> 4) * 4;
    int c0 = lane & 15;
    float bv[16];
    if (BIAS) {
#pragma unroll
        for (int nf = 0; nf < 16; ++nf) bv[nf] = bias[nf * 16 + c0];
    }
#pragma unroll
    for (int mf = 0; mf < 2; ++mf)
#pragma unroll
        for (int r = 0; r < 4; ++r) {
            int row = rbase + mf * 16 + rg + r;
            if (row < rows) {
#pragma unroll
                for (int nf = 0; nf < 16; ++nf) {
                    float v = acc[mf][nf][r];
                    if (BIAS) v += bv[nf];
                    outb[(size_t)row * HID + nf * 16 + c0] = f2bf(v);
                }
            }
        }

    if (ATT) {
        float as[16], ad[16];
#pragma unroll
        for (int nf = 0; nf < 16; ++nf) {
            as[nf] = att_s[nf * 16 + c0];
            ad[nf] = att_d[nf * 16 + c0];
        }
#pragma unroll
        for (int mf = 0; mf < 2; ++mf)
#pragma unroll
            for (int r = 0; r < 4; ++r) {
                float ps[4] = {0.f, 0.f, 0.f, 0.f}, pd[4] = {0.f, 0.f, 0.f, 0.f};
#pragma unroll
                for (int nf = 0; nf < 16; ++nf) {
                    float v = acc[mf][nf][r];
                    ps[nf >> 2] += v * as[nf];
                    pd[nf >> 2] += v * ad[nf];
                }
#pragma unroll
                for (int o = 1; o < 16; o <<= 1) {
#pragma unroll
                    for (int h = 0; h < 4; ++h) {
                        ps[h] += __shfl_xor(ps[h], o, 64);
                        pd[h] += __shfl_xor(pd[h], o, 64);
                    }
                }
                int row = rbase + mf * 16 + rg + r;
                if (c0 == 0 && row < rows) {
                    float4 vs, vd;
                    vs.x = ps[0]; vs.y = ps[1]; vs.z = ps[2]; vs.w = ps[3];
                    vd.x = pd[0]; vd.y = pd[1]; vd.z = pd[2]; vd.w = pd[3];
                    *(float4*)(al_s + row * 4) = vs;
                    *(float4*)(al_d + row * 4) = vd;
                }
            }
    }
}

// ---------------- GAT aggregation + bias + residual + LayerNorm ----------------
// One WAVE per node, no LDS, no barriers.
// lane = es(4 edge slots) x cg(16 channel groups of 16 channels); head = cg>>2.

__global__ __launch_bounds__(256, 4) void k_agg(
    const ushort* __restrict__ hb, const ushort* __restrict__ xs,
    const float* __restrict__ al_s, const float* __restrict__ al_d,
    const int* __restrict__ off, const int* __restrict__ csr,
    const int* __restrict__ batch, const int* __restrict__ lo,
    const int* __restrict__ hi,
    const float* __restrict__ b_gat, const float* __restrict__ ln_g,
    const float* __restrict__ ln_b,
    ushort* __restrict__ h_out, int n_new, int B)
{
    int t = threadIdx.x, w = t >> 6, lane = t & 63;
    int n = blockIdx.x * 4 + w;
    if (n >= n_new) return;
    int es = lane >> 4, cg = lane & 15, head = cg >> 2;

    int gbeg = 0, gdeg = 0, cbeg = 0, cdeg = 0;
    if (n >= B) { gbeg = off[n]; gdeg = off[n + 1] - gbeg; cdeg = 1; }
    else { cbeg = lo[n]; cdeg = hi[n] - cbeg; }
    int cnt = gdeg + cdeg + 1;
    int clssrc = (n >= B) ? batch[n - B] : 0;

    float4 ald = *(const float4*)(al_d + n * 4);

    // ---- phase 1: online softmax stats (m,s) per head, lane-strided ----
    float m0 = -1e30f, m1 = -1e30f, m2 = -1e30f, m3 = -1e30f;
    float s0 = 0.f, s1 = 0.f, s2 = 0.f, s3 = 0.f;
    for (int e = lane; e < cnt; e += 64) {
        int src;
        if (e < gdeg) src = csr[gbeg + e];
        else if (e < gdeg + cdeg) src = (n >= B) ? clssrc : (B + cbeg + (e - gdeg));
        else src = n;
        float4 a4 = *(const float4*)(al_s + src * 4);
        float v0 = a4.x + ald.x; v0 = v0 > 0.f ? v0 : NEG * v0;
        float v1 = a4.y + ald.y; v1 = v1 > 0.f ? v1 : NEG * v1;
        float v2 = a4.z + ald.z; v2 = v2 > 0.f ? v2 : NEG * v2;
        float v3 = a4.w + ald.w; v3 = v3 > 0.f ? v3 : NEG * v3;
        float mn;
        mn = fmaxf(m0, v0); s0 = s0 * __expf(m0 - mn) + __expf(v0 - mn); m0 = mn;
        mn = fmaxf(m1, v1); s1 = s1 * __expf(m1 - mn) + __expf(v1 - mn); m1 = mn;
        mn = fmaxf(m2, v2); s2 = s2 * __expf(m2 - mn) + __expf(v2 - mn); m2 = mn;
        mn = fmaxf(m3, v3); s3 = s3 * __expf(m3 - mn) + __expf(v3 - mn); m3 = mn;
    }
#pragma unroll
    for (int o = 32; o > 0; o >>= 1) {
        float mo, so, mn;
        mo = __shfl_xor(m0, o, 64); so = __shfl_xor(s0, o, 64);
        mn = fmaxf(m0, mo); s0 = s0 * __expf(m0 - mn) + so * __expf(mo - mn); m0 = mn;
        mo = __shfl_xor(m1, o, 64); so = __shfl_xor(s1, o, 64);
        mn = fmaxf(m1, mo); s1 = s1 * __expf(m1 - mn) + so * __expf(mo - mn); m1 = mn;
        mo = __shfl_xor(m2, o, 64); so = __shfl_xor(s2, o, 64);
        mn = fmaxf(m2, mo); s2 = s2 * __expf(m2 - mn) + so * __expf(mo - mn); m2 = mn;
        mo = __shfl_xor(m3, o, 64); so = __shfl_xor(s3, o, 64);
        mn = fmaxf(m3, mo); s3 = s3 * __expf(m3 - mn) + so * __expf(mo - mn); m3 = mn;
    }
    float m_h = head == 0 ? m0 : head == 1 ? m1 : head == 2 ? m2 : m3;
    float s_h = head == 0 ? s0 : head == 1 ? s1 : head == 2 ? s2 : s3;
    float inv_h = 1.f / (s_h + 1e-16f);
    float ald_h = head == 0 ? ald.x : head == 1 ? ald.y : head == 2 ? ald.z : ald.w;

    // ---- phase 2: weighted gather, 4 edges in flight, 16 ch/lane ----
    float acc[16];
#pragma unroll
    for (int j = 0; j < 16; ++j) acc[j] = 0.f;

#pragma unroll 2
    for (int eb = 0; eb < cnt; eb += 4) {
        int e = eb + es;
        if (e < cnt) {
            int src;
            if (e < gdeg) src = csr[gbeg + e];
            else if (e < gdeg + cdeg) src = (n >= B) ? clssrc : (B + cbeg + (e - gdeg));
            else src = n;
            const float* ap = al_s + src * 4;
            float as_h = ap[head];
            float vh = as_h + ald_h;
            vh = vh > 0.f ? vh : NEG * vh;
            float a = __expf(vh - m_h);
            const bf16x8* xp = (const bf16x8*)(xs + (size_t)src * HID) + cg * 2;
            bf16x8 x0 = xp[0], x1 = xp[1];
#pragma unroll
            for (int j = 0; j < 8; ++j) {
                acc[j]     += a * bf2f((unsigned short)x0[j]);
                acc[8 + j] += a * bf2f((unsigned short)x1[j]);
            }
        }
    }

    // reduce across edge slots (xor bits 4,5)
#pragma unroll
    for (int o = 16; o < 64; o <<= 1)
#pragma unroll
        for (int j = 0; j < 16; ++j) acc[j] += __shfl_xor(acc[j], o, 64);

    // residual + bias
    const bf16x8* hp = (const bf16x8*)(hb + (size_t)n * HID) + cg * 2;
    bf16x8 hv0 = hp[0], hv1 = hp[1];
    const float4* bgp = (const float4*)(b_gat + cg * 16);
    float4 bg0 = bgp[0], bg1 = bgp[1], bg2 = bgp[2], bg3 = bgp[3];
    float bg[16] = {bg0.x, bg0.y, bg0.z, bg0.w, bg1.x, bg1.y, bg1.z, bg1.w,
                    bg2.x, bg2.y, bg2.z, bg2.w, bg3.x, bg3.y, bg3.z, bg3.w};
    float r[16];
#pragma unroll
    for (int j = 0; j < 8; ++j) {
        r[j]     = bf2f((unsigned short)hv0[j]) + acc[j] * inv_h + bg[j];
        r[8 + j] = bf2f((unsigned short)hv1[j]) + acc[8 + j] * inv_h + bg[8 + j];
    }

    // LayerNorm: reduce across the 16 channel groups (xor bits 0..3)
    float ss = 0.f;
#pragma unroll
    for (int j = 0; j < 16; ++j) ss += r[j];
#pragma unroll
    for (int o = 1; o < 16; o <<= 1) ss += __shfl_xor(ss, o, 64);
    float mu = ss * (1.f / HID);
    float vv = 0.f;
#pragma unroll
    for (int j = 0; j < 16; ++j) { r[j] -= mu; vv += r[j] * r[j]; }
#pragma unroll
    for (int o = 1; o < 16; o <<= 1) vv += __shfl_xor(vv, o, 64);
    float rs = rsqrtf(vv * (1.f / HID) + EPS);

    if (es == 0) {
        const float4* gp = (const float4*)(ln_g + cg * 16);
        const float4* bp = (const float4*)(ln_b + cg * 16);
        float4 g0 = gp[0], g1 = gp[1], g2 = gp[2], g3 = gp[3];
        float4 lb0 = bp[0], lb1 = bp[1], lb2 = bp[2], lb3 = bp[3];
        float gg[16] = {g0.x, g0.y, g0.z, g0.w, g1.x, g1.y, g1.z, g1.w,
                        g2.x, g2.y, g2.z, g2.w, g3.x, g3.y, g3.z, g3.w};
        float bb[16] = {lb0.x, lb0.y, lb0.z, lb0.w, lb1.x, lb1.y, lb1.z, lb1.w,
                        lb2.x, lb2.y, lb2.z, lb2.w, lb3.x, lb3.y, lb3.z, lb3.w};
        bf16x8 o0, o1;
#pragma unroll
        for (int j = 0; j < 8; ++j) {
            o0[j] = (short)f2bf(r[j] * rs * gg[j] + bb[j]);
            o1[j] = (short)f2bf(r[8 + j] * rs * gg[8 + j] + bb[8 + j]);
        }
        bf16x8* op = (bf16x8*)(h_out + (size_t)n * HID) + cg * 2;
        op[0] = o0;
        op[1] = o1;
    }
}

// ---------------- output projection (B x 256 @ 256 x 256) ----------------

__global__ __launch_bounds__(256) void k_out(
    const ushort* __restrict__ h, const float* __restrict__ Wm,
    const float* __restrict__ bias, float* __restrict__ z)
{
    __shared__ float hs[HID];
    int b = blockIdx.x, t = threadIdx.x;
    hs[t] = bf2f(h[(size_t)b * HID + t]);
    __syncthreads();
    float acc = bias[t];
#pragma unroll 8
    for (int k = 0; k < HID; ++k) acc += hs[k] * Wm[k * HID + t];
    z[(size_t)b * HID + t] = acc;
}

// ---------------- launch ----------------

extern "C" void kernel_launch(void* const* d_in, const int* in_sizes, int n_in,
                              void* d_out, int out_size, void* d_ws, size_t ws_size,
                              hipStream_t stream) {
    const float* x      = (const float*)d_in[0];
    const int*   ei     = (const int*)d_in[1];
    const int*   batch  = (const int*)d_in[2];
    const float* W_in   = (const float*)d_in[3];
    const float* b_in   = (const float*)d_in[4];
    const float* cls    = (const float*)d_in[5];
    const float* W_gat  = (const float*)d_in[6];
    const float* att_s  = (const float*)d_in[7];
    const float* att_d  = (const float*)d_in[8];
    const float* b_gat  = (const float*)d_in[9];
    const float* ln_g   = (const float*)d_in[10];
    const float* ln_b   = (const float*)d_in[11];
    const float* W_out  = (const float*)d_in[12];
    const float* b_out  = (const float*)d_in[13];

    const int N = in_sizes[0] / 128;
    const int E = in_sizes[1] / 2;
    const int B = 64;
    const int n_new = N + B;
    const int* src0 = ei;
    const int* dst0 = ei + E;

    char* p = (char*)d_ws;
    auto alloc = [&](size_t bytes) -> void* {
        void* r = (void*)p;
        p += (bytes + 255) & ~(size_t)255;
        return r;
    };
    int*    off    = (int*)alloc((size_t)(n_new + 1) * 4);
    int*    deg    = (int*)alloc((size_t)n_new * 4);
    int*    cursor = (int*)alloc((size_t)n_new * 4);
    int*    csr    = (int*)alloc((size_t)E * 4);
    int*    lo     = (int*)alloc((size_t)B * 4);
    int*    hi     = (int*)alloc((size_t)B * 4);
    ushort* xb     = (ushort*)alloc((size_t)N * 128 * 2);
    ushort* h0b    = (ushort*)alloc((size_t)n_new * HID * 2);
    ushort* h1b    = (ushort*)alloc((size_t)n_new * HID * 2);
    ushort* xsb    = (ushort*)alloc((size_t)n_new * HID * 2);
    float*  als    = (float*)alloc((size_t)n_new * 4 * 4);
    float*  aldv   = (float*)alloc((size_t)n_new * 4 * 4);
    ushort* wf_in  = (ushort*)alloc((size_t)4 * 1024 * 8 * 2);
    ushort* wf_gat = (ushort*)alloc((size_t)3 * 8 * 1024 * 8 * 2);

    k_init<<<(n_new + 255) / 256, 256, 0, stream>>>(deg, cursor, lo, hi, n_new, B);
    k_count<<<(E + 255) / 256, 256, 0, stream>>>(dst0, deg, E, B);
    k_scan<<<1, 1024, 0, stream>>>(deg, off, n_new);
    k_fill<<<(E + 255) / 256, 256, 0, stream>>>(src0, dst0, off, cursor, csr, E, B);
    k_bounds<<<(N + 255) / 256, 256, 0, stream>>>(batch, lo, hi, N);

    k_cvt<<<(N * 128 / 4 + 255) / 256, 256, 0, stream>>>(x, xb, N * 128 / 4);
    k_cls<<<(B * HID + 255) / 256, 256, 0, stream>>>(cls, h0b, B);
    k_frag<<<(4 * 1024 + 255) / 256, 256, 0, stream>>>(W_in, wf_in, 4, 1);
    k_frag<<<(3 * 8 * 1024 + 255) / 256, 256, 0, stream>>>(W_gat, wf_gat, 8, 3);

    k_mgemm<4, false, true><<<(N + 63) / 64, 128, 0, stream>>>(
        xb, wf_in, b_in, h0b + (size_t)B * HID, nullptr, nullptr, nullptr, nullptr, N);

    ushort* cur = h0b;
    ushort* nxt = h1b;
    for (int l = 0; l < 3; ++l) {
        k_mgemm<8, true, false><<<(n_new + 63) / 64, 128, 0, stream>>>(
            cur, wf_gat + (size_t)l * 65536, nullptr, xsb,
            att_s + l * HID, att_d + l * HID, als, aldv, n_new);
        k_agg<<<(n_new + 3) / 4, 256, 0, stream>>>(
            cur, xsb, als, aldv, off, csr, batch, lo, hi,
            b_gat + l * HID, ln_g + l * HID, ln_b + l * HID, nxt, n_new, B);
        ushort* tmp = cur; cur = nxt; nxt = tmp;
    }
    k_out<<<B, 256, 0, stream>>>(cur, W_out, b_out, (float*)d_out);
}